// Round 1
// 2142.808 us; speedup vs baseline: 2.9443x; 2.9443x over previous
//
#include <hip/hip_runtime.h>
#include <stdint.h>

// SharedLSTM: B=64, S=512, D=512.
//  out = concat(hidden_seq [64,512,512], h_T [64,512], c_T [64,512]) fp32.
//
// Pipeline:
//  1) convert cas|social -> Xcat bf16 [32768][1024] (row r = b*512+s)
//  2) transpose-convert [W;U] -> WUt bf16 [2048 n][1024 k], V -> Vt bf16 [2048 n][512 k]
//  3) MFMA GEMM: x_proj[s*64+b][n] = Xcat@WUcat + bias   (bf16 out, fp32 acc)
//  4) persistent recurrence kernel: 64 wgs (4 batch-groups x 16 d-groups),
//     V^T held entirely in VGPRs. Cross-wg sync per step uses cache-bypassing
//     (sc0/sc1) stores+loads and distributed per-wg flags — NO threadfence
//     (no buffer_wbl2/buffer_inv L2 flushes), NO contended atomicAdd.
//
// ws layout:
//   [0,4096)          per-wg arrival flags (memset each launch)
//   [4096, +131072)   h ping-pong bf16 [2][64][512] (memset each launch)
//   [262144, +134217728)  x_proj bf16 [32768][2048]
//   then Xcat (67MB), WUt (4MB), Vt (2MB)

typedef __attribute__((ext_vector_type(8))) short short8;
typedef __attribute__((ext_vector_type(4))) float f32x4;
typedef __attribute__((ext_vector_type(2))) float f32x2;
typedef __attribute__((ext_vector_type(4))) unsigned int u32x4v;

__device__ __forceinline__ unsigned short f2bf(float x) {
  union { float f; unsigned v; } c; c.f = x;
  unsigned r = (c.v + 0x7fffu + ((c.v >> 16) & 1u)) >> 16;  // RNE
  return (unsigned short)r;
}
__device__ __forceinline__ float bf2f(unsigned short u) {
  union { unsigned v; float f; } c; c.v = (unsigned)u << 16; return c.f;
}
__device__ __forceinline__ float sigm(float x) { return 1.f / (1.f + __expf(-x)); }
__device__ __forceinline__ float tanh_f(float x) { return 1.f - 2.f / (__expf(2.f * x) + 1.f); }

// ---------------- 1) concat + fp32->bf16 ----------------
__global__ __launch_bounds__(256) void k_convX(const float* __restrict__ cas,
                                               const float* __restrict__ soc,
                                               unsigned short* __restrict__ Xcat) {
  size_t i = ((size_t)blockIdx.x * 256 + threadIdx.x) * 8;  // elem in 32768*1024
  int r = (int)(i >> 10), k0 = (int)(i & 1023);
  const float* src = (k0 < 512) ? cas + (size_t)r * 512 + k0
                                : soc + (size_t)r * 512 + (k0 - 512);
  f32x4 a = *(const f32x4*)src;
  f32x4 b = *(const f32x4*)(src + 4);
  short8 o;
  o[0] = (short)f2bf(a[0]); o[1] = (short)f2bf(a[1]);
  o[2] = (short)f2bf(a[2]); o[3] = (short)f2bf(a[3]);
  o[4] = (short)f2bf(b[0]); o[5] = (short)f2bf(b[1]);
  o[6] = (short)f2bf(b[2]); o[7] = (short)f2bf(b[3]);
  *(short8*)(Xcat + i) = o;
}

// ---------------- 2) transpose + convert: Out[n][kk] = src(kk,n) -----------
__global__ __launch_bounds__(256) void k_transpose(const float* __restrict__ S0,
                                                   const float* __restrict__ S1,
                                                   int split, int Ktot,
                                                   unsigned short* __restrict__ Out) {
  __shared__ float tile[64][65];
  int tk = blockIdx.x, tn = blockIdx.y, tid = threadIdx.x;
#pragma unroll
  for (int i = 0; i < 16; ++i) {
    int idx = i * 256 + tid;
    int kr = idx >> 6, nc = idx & 63;
    int kk = tk * 64 + kr;
    const float* s = (kk < split) ? S0 + (size_t)kk * 2048 + tn * 64 + nc
                                  : S1 + (size_t)(kk - split) * 2048 + tn * 64 + nc;
    tile[kr][nc] = *s;
  }
  __syncthreads();
#pragma unroll
  for (int i = 0; i < 16; ++i) {
    int idx = i * 256 + tid;
    int nr = idx >> 6, kc = idx & 63;
    Out[(size_t)(tn * 64 + nr) * Ktot + tk * 64 + kc] = f2bf(tile[kc][nr]);
  }
}

// ---------------- 3) x_proj GEMM: 128x128 tile, BK=32, global_load_lds ------
__global__ __launch_bounds__(256) void k_gemm(const unsigned short* __restrict__ A,
                                              const unsigned short* __restrict__ Bt,
                                              const float* __restrict__ bias,
                                              unsigned short* __restrict__ xproj) {
  __shared__ __attribute__((aligned(16))) unsigned short At[128 * 32];
  __shared__ __attribute__((aligned(16))) unsigned short Bs[128 * 32];
  int tn0 = blockIdx.x * 128, tm0 = blockIdx.y * 128;
  int tid = threadIdx.x, wave = tid >> 6, lane = tid & 63;
  int wr = wave >> 1, wc = wave & 1;
  f32x4 acc[4][4] = {};

  for (int kt = 0; kt < 32; ++kt) {
    __syncthreads();
#pragma unroll
    for (int i = 0; i < 2; ++i) {
      int cb = i * 256 + wave * 64;
      int c = cb + lane;
      const unsigned short* ga = A + (size_t)(tm0 + (c >> 2)) * 1024 + kt * 32 + (c & 3) * 8;
      __builtin_amdgcn_global_load_lds((const __attribute__((address_space(1))) void*)ga,
                                       (__attribute__((address_space(3))) void*)(At + cb * 8),
                                       16, 0, 0);
      const unsigned short* gb = Bt + (size_t)(tn0 + (c >> 2)) * 1024 + kt * 32 + (c & 3) * 8;
      __builtin_amdgcn_global_load_lds((const __attribute__((address_space(1))) void*)gb,
                                       (__attribute__((address_space(3))) void*)(Bs + cb * 8),
                                       16, 0, 0);
    }
    __syncthreads();
    short8 af[4], bf[4];
#pragma unroll
    for (int m = 0; m < 4; ++m)
      af[m] = *(const short8*)(At + (wr * 64 + m * 16 + (lane & 15)) * 32 + (lane >> 4) * 8);
#pragma unroll
    for (int n = 0; n < 4; ++n)
      bf[n] = *(const short8*)(Bs + (wc * 64 + n * 16 + (lane & 15)) * 32 + (lane >> 4) * 8);
#pragma unroll
    for (int m = 0; m < 4; ++m)
#pragma unroll
      for (int n = 0; n < 4; ++n)
        acc[m][n] = __builtin_amdgcn_mfma_f32_16x16x32_bf16(af[m], bf[n], acc[m][n], 0, 0, 0);
  }

#pragma unroll
  for (int n = 0; n < 4; ++n) {
    int cg = tn0 + wc * 64 + n * 16 + (lane & 15);
    float bv = bias[cg];
#pragma unroll
    for (int m = 0; m < 4; ++m) {
#pragma unroll
      for (int rr = 0; rr < 4; ++rr) {
        int rg = tm0 + wr * 64 + m * 16 + ((lane >> 4) << 2) + rr;  // r = b*512+s
        int orow = ((rg & 511) << 6) | (rg >> 9);                   // s*64+b
        xproj[(size_t)orow * 2048 + cg] = f2bf(acc[m][n][rr] + bv);
      }
    }
  }
}

// ---------------- 4) persistent recurrence ----------------
// 64 wgs: g = bg*16+dg ... bg=batch group (16 batches), dg=d group (32 d).
// wave w = gate w (i,f,g,o); owns V^T rows [w*512+dg*32, +32) in VGPRs.
//
// Per-step protocol (no threadfence, no contended atomics):
//   producer side:  h stored via relaxed AGENT atomic stores (sc1, write-through
//                   to coherence point) -> __syncthreads() (drains vmcnt(0)) ->
//                   tid0 publishes flags[dg] = t+1 (relaxed AGENT store).
//   consumer side:  all waves spin lane-parallel on the 16 flags (relaxed AGENT
//                   loads) until all >= t, then read h fragments with
//                   cache-bypassing global_load_dwordx4 ... sc0 sc1.
__global__ __launch_bounds__(256, 1) void k_lstm(const unsigned short* __restrict__ xproj,
                                                 const unsigned short* __restrict__ Vt,
                                                 unsigned short* __restrict__ hbuf,
                                                 float* __restrict__ out,
                                                 int* __restrict__ flags) {
  int g = blockIdx.x;
  int bg = g >> 4, dg = g & 15;
  int tid = threadIdx.x, wave = tid >> 6, lane = tid & 63;

  // V fragments resident across the whole kernel: 2 tiles x 16 k-steps x 4 VGPR
  short8 vfrag[2][16];
#pragma unroll
  for (int hh = 0; hh < 2; ++hh)
#pragma unroll
    for (int kt = 0; kt < 16; ++kt) {
      int n = wave * 512 + dg * 32 + hh * 16 + (lane & 15);
      vfrag[hh][kt] = *(const short8*)(Vt + (size_t)n * 512 + kt * 32 + (lane >> 4) * 8);
    }

  __shared__ float gbuf[4][16][32];                                   // raw gates
  __shared__ __attribute__((aligned(16))) unsigned short xbuf[4][16][32];  // x_proj slice

  float c0 = 0.f, c1 = 0.f;          // cell state lives in registers
  int br = tid >> 4;                 // batch row 0..15
  int dc = (tid & 15) * 2;           // d col (pair)
  int batch = bg * 16 + br;
  int dglob = dg * 32 + dc;

  int xb = tid >> 4, xq = (tid >> 2) & 3, xs = tid & 3;
  const unsigned short* xrow = xproj + (size_t)(bg * 16 + xb) * 2048 + xq * 512 + dg * 32 + xs * 8;
  int* myflags = flags + bg * 16;    // 16 consecutive ints (one 64B line) per group

  // per-lane base for the coherent h-fragment loads (byte-addressed below)
  const unsigned short* hlane0 =
      hbuf + (size_t)((bg * 16 + (lane & 15)) * 512 + (lane >> 4) * 8);

  for (int t = 0; t < 512; ++t) {
    // prefetch x_proj slice under the spin (normal cached load)
    short8 xv = *(const short8*)(xrow + (size_t)t * 64 * 2048);

    // ---- wait for all 16 wgs of this batch group to finish step t-1 ----
    if (t) {
      while (true) {
        int v = __hip_atomic_load(myflags + (lane & 15), __ATOMIC_RELAXED,
                                  __HIP_MEMORY_SCOPE_AGENT);
        if (__all(v >= t)) break;
        __builtin_amdgcn_s_sleep(1);
      }
    }

    // ---- coherent h fragment loads (bypass L1/L2; h is at coherence point) ----
    const unsigned short* hb = hlane0 + ((size_t)(t & 1) << 15);
    u32x4v f0, f1, f2, f3, f4, f5, f6, f7, f8, f9, f10, f11, f12, f13, f14, f15;
    asm volatile(
        "global_load_dwordx4 %0, %16, off sc0 sc1\n\t"
        "global_load_dwordx4 %1, %16, off offset:64 sc0 sc1\n\t"
        "global_load_dwordx4 %2, %16, off offset:128 sc0 sc1\n\t"
        "global_load_dwordx4 %3, %16, off offset:192 sc0 sc1\n\t"
        "global_load_dwordx4 %4, %16, off offset:256 sc0 sc1\n\t"
        "global_load_dwordx4 %5, %16, off offset:320 sc0 sc1\n\t"
        "global_load_dwordx4 %6, %16, off offset:384 sc0 sc1\n\t"
        "global_load_dwordx4 %7, %16, off offset:448 sc0 sc1\n\t"
        "global_load_dwordx4 %8, %16, off offset:512 sc0 sc1\n\t"
        "global_load_dwordx4 %9, %16, off offset:576 sc0 sc1\n\t"
        "global_load_dwordx4 %10, %16, off offset:640 sc0 sc1\n\t"
        "global_load_dwordx4 %11, %16, off offset:704 sc0 sc1\n\t"
        "global_load_dwordx4 %12, %16, off offset:768 sc0 sc1\n\t"
        "global_load_dwordx4 %13, %16, off offset:832 sc0 sc1\n\t"
        "global_load_dwordx4 %14, %16, off offset:896 sc0 sc1\n\t"
        "global_load_dwordx4 %15, %16, off offset:960 sc0 sc1\n\t"
        "s_waitcnt vmcnt(0)"
        : "=&v"(f0), "=&v"(f1), "=&v"(f2), "=&v"(f3), "=&v"(f4), "=&v"(f5),
          "=&v"(f6), "=&v"(f7), "=&v"(f8), "=&v"(f9), "=&v"(f10), "=&v"(f11),
          "=&v"(f12), "=&v"(f13), "=&v"(f14), "=&v"(f15)
        : "v"(hb)
        : "memory");

    short8 afr[16];
    afr[0]  = __builtin_bit_cast(short8, f0);
    afr[1]  = __builtin_bit_cast(short8, f1);
    afr[2]  = __builtin_bit_cast(short8, f2);
    afr[3]  = __builtin_bit_cast(short8, f3);
    afr[4]  = __builtin_bit_cast(short8, f4);
    afr[5]  = __builtin_bit_cast(short8, f5);
    afr[6]  = __builtin_bit_cast(short8, f6);
    afr[7]  = __builtin_bit_cast(short8, f7);
    afr[8]  = __builtin_bit_cast(short8, f8);
    afr[9]  = __builtin_bit_cast(short8, f9);
    afr[10] = __builtin_bit_cast(short8, f10);
    afr[11] = __builtin_bit_cast(short8, f11);
    afr[12] = __builtin_bit_cast(short8, f12);
    afr[13] = __builtin_bit_cast(short8, f13);
    afr[14] = __builtin_bit_cast(short8, f14);
    afr[15] = __builtin_bit_cast(short8, f15);

    f32x4 a0 = {0.f, 0.f, 0.f, 0.f}, a1 = {0.f, 0.f, 0.f, 0.f};
#pragma unroll
    for (int kt = 0; kt < 16; ++kt) {
      a0 = __builtin_amdgcn_mfma_f32_16x16x32_bf16(afr[kt], vfrag[0][kt], a0, 0, 0, 0);
      a1 = __builtin_amdgcn_mfma_f32_16x16x32_bf16(afr[kt], vfrag[1][kt], a1, 0, 0, 0);
    }

    *(short8*)&xbuf[xq][xb][xs * 8] = xv;
#pragma unroll
    for (int rr = 0; rr < 4; ++rr) {
      gbuf[wave][((lane >> 4) << 2) + rr][lane & 15] = a0[rr];
      gbuf[wave][((lane >> 4) << 2) + rr][16 + (lane & 15)] = a1[rr];
    }
    __syncthreads();

    // elementwise: 2 (b,d) elems per thread
    f32x2 vi = *(const f32x2*)&gbuf[0][br][dc];
    f32x2 vf = *(const f32x2*)&gbuf[1][br][dc];
    f32x2 vg = *(const f32x2*)&gbuf[2][br][dc];
    f32x2 vo = *(const f32x2*)&gbuf[3][br][dc];
    unsigned xi = *(const unsigned*)&xbuf[0][br][dc];
    unsigned xf = *(const unsigned*)&xbuf[1][br][dc];
    unsigned xg = *(const unsigned*)&xbuf[2][br][dc];
    unsigned xo = *(const unsigned*)&xbuf[3][br][dc];

    float i0 = sigm(vi[0] + bf2f((unsigned short)xi));
    float i1 = sigm(vi[1] + bf2f((unsigned short)(xi >> 16)));
    float f0v = sigm(vf[0] + bf2f((unsigned short)xf));
    float f1v = sigm(vf[1] + bf2f((unsigned short)(xf >> 16)));
    float g0 = tanh_f(vg[0] + bf2f((unsigned short)xg));
    float g1 = tanh_f(vg[1] + bf2f((unsigned short)(xg >> 16)));
    float o0 = sigm(vo[0] + bf2f((unsigned short)xo));
    float o1 = sigm(vo[1] + bf2f((unsigned short)(xo >> 16)));

    c0 = f0v * c0 + i0 * g0;
    c1 = f1v * c1 + i1 * g1;
    float h0 = o0 * tanh_f(c0);
    float h1 = o1 * tanh_f(c1);

    // h store: relaxed agent-scope atomic (sc1 write-through, no L2 flush needed)
    unsigned short* hn = hbuf + (((t + 1) & 1) << 15);
    unsigned hp = (unsigned)f2bf(h0) | ((unsigned)f2bf(h1) << 16);
    __hip_atomic_store((unsigned*)(hn + batch * 512 + dglob), hp,
                       __ATOMIC_RELAXED, __HIP_MEMORY_SCOPE_AGENT);
    f32x2 hv = {h0, h1};
    *(f32x2*)(out + (size_t)batch * 262144 + (size_t)t * 512 + dglob) = hv;
    if (t == 511) {
      *(f32x2*)(out + 16777216 + batch * 512 + dglob) = hv;
      f32x2 cv = {c0, c1};
      *(f32x2*)(out + 16809984 + batch * 512 + dglob) = cv;
    }

    // __syncthreads drains vmcnt(0): all this wg's h stores are at the
    // coherence point before tid0 publishes the arrival flag.
    __syncthreads();
    if (tid == 0)
      __hip_atomic_store(myflags + dg, t + 1, __ATOMIC_RELAXED,
                         __HIP_MEMORY_SCOPE_AGENT);
  }
}

extern "C" void kernel_launch(void* const* d_in, const int* in_sizes, int n_in,
                              void* d_out, int out_size, void* d_ws, size_t ws_size,
                              hipStream_t stream) {
  const float* cas  = (const float*)d_in[0];
  const float* soc  = (const float*)d_in[1];
  const float* W    = (const float*)d_in[2];
  const float* U    = (const float*)d_in[3];
  const float* V    = (const float*)d_in[4];
  const float* bias = (const float*)d_in[5];
  float* out = (float*)d_out;
  char* ws = (char*)d_ws;

  int* flags            = (int*)ws;                        // 4KB
  unsigned short* hbuf  = (unsigned short*)(ws + 4096);    // 128KB (2 bufs)
  unsigned short* xproj = (unsigned short*)(ws + 262144);  // 134,217,728 B
  unsigned short* Xcat  = xproj + (size_t)32768 * 2048;    // 67,108,864 B
  unsigned short* WUt   = Xcat + (size_t)32768 * 1024;     // 4,194,304 B
  unsigned short* Vt    = WUt + (size_t)2048 * 1024;       // 2,097,152 B

  // reset arrival flags + h0-era h buffers (c lives in registers)
  hipMemsetAsync(ws, 0, 4096 + 131072, stream);

  k_convX<<<16384, 256, 0, stream>>>(cas, soc, Xcat);
  k_transpose<<<dim3(16, 32), 256, 0, stream>>>(W, U, 512, 1024, WUt);
  k_transpose<<<dim3(8, 32), 256, 0, stream>>>(V, V, 512, 512, Vt);
  k_gemm<<<dim3(16, 256), 256, 0, stream>>>(Xcat, WUt, bias, xproj);
  k_lstm<<<64, 256, 0, stream>>>(xproj, Vt, hbuf, out, flags);
}

// Round 4
// 1826.746 us; speedup vs baseline: 3.4537x; 1.1730x over previous
//
#include <hip/hip_runtime.h>
#include <stdint.h>

// SharedLSTM: B=64, S=512, D=512.
//  out = concat(hidden_seq [64,512,512], h_T [64,512], c_T [64,512]) fp32.
//
// Pipeline:
//  1) convert cas|social -> Xcat bf16 [32768][1024] (row r = b*512+s)
//  2) transpose-convert [W;U] -> WUt bf16 [2048 n][1024 k], V -> Vt bf16 [2048 n][512 k]
//  3) MFMA GEMM: x_proj[s*64+b][n] = Xcat@WUcat + bias   (bf16 out, fp32 acc)
//  4) persistent recurrence, EPOCH-STAMPED protocol (round 4):
//     64 wgs = 4 batch-groups x 16 d-groups, V^T in VGPRs as round 1.
//     h is stored as stamped dwords (bf16 h | epoch<<16) with sc0 sc1 —
//     fire-and-forget, no drain, no flags. Consumers poll the DATA until
//     every stamp == t (detect and load are the same round trip; dword
//     atomicity keeps h+stamp together). Ping-pong slots; flow control is
//     emergent (writer of stamp t+2 must first observe all stamps t+1).
//     Each wave polls 1/4 of the fragment and shares via padded LDS.
//     All cross-wg traffic is device-scope (sc0 sc1) — no placement bets.
//
// ws layout:
//   [0, 262144)       x_proj region starts at 262144 as before
//   [262144, +134217728)  x_proj bf16 [32768][2048]
//   then Xcat (67MB) — REUSED after k_gemm as the stamped-h buffer sh
//        (memset 256KB between k_gemm and k_lstm), WUt (4MB), Vt (2MB)

typedef __attribute__((ext_vector_type(8))) short short8;
typedef __attribute__((ext_vector_type(4))) float f32x4;
typedef __attribute__((ext_vector_type(2))) float f32x2;
typedef __attribute__((ext_vector_type(4))) unsigned int u32x4v;
typedef __attribute__((ext_vector_type(2))) unsigned int u32x2v;

__device__ __forceinline__ unsigned short f2bf(float x) {
  union { float f; unsigned v; } c; c.f = x;
  unsigned r = (c.v + 0x7fffu + ((c.v >> 16) & 1u)) >> 16;  // RNE
  return (unsigned short)r;
}
__device__ __forceinline__ float bf2f(unsigned short u) {
  union { unsigned v; float f; } c; c.v = (unsigned)u << 16; return c.f;
}
__device__ __forceinline__ float sigm(float x) { return 1.f / (1.f + __expf(-x)); }
__device__ __forceinline__ float tanh_f(float x) { return 1.f - 2.f / (__expf(2.f * x) + 1.f); }

// ---------------- 1) concat + fp32->bf16 ----------------
__global__ __launch_bounds__(256) void k_convX(const float* __restrict__ cas,
                                               const float* __restrict__ soc,
                                               unsigned short* __restrict__ Xcat) {
  size_t i = ((size_t)blockIdx.x * 256 + threadIdx.x) * 8;  // elem in 32768*1024
  int r = (int)(i >> 10), k0 = (int)(i & 1023);
  const float* src = (k0 < 512) ? cas + (size_t)r * 512 + k0
                                : soc + (size_t)r * 512 + (k0 - 512);
  f32x4 a = *(const f32x4*)src;
  f32x4 b = *(const f32x4*)(src + 4);
  short8 o;
  o[0] = (short)f2bf(a[0]); o[1] = (short)f2bf(a[1]);
  o[2] = (short)f2bf(a[2]); o[3] = (short)f2bf(a[3]);
  o[4] = (short)f2bf(b[0]); o[5] = (short)f2bf(b[1]);
  o[6] = (short)f2bf(b[2]); o[7] = (short)f2bf(b[3]);
  *(short8*)(Xcat + i) = o;
}

// ---------------- 2) transpose + convert: Out[n][kk] = src(kk,n) -----------
__global__ __launch_bounds__(256) void k_transpose(const float* __restrict__ S0,
                                                   const float* __restrict__ S1,
                                                   int split, int Ktot,
                                                   unsigned short* __restrict__ Out) {
  __shared__ float tile[64][65];
  int tk = blockIdx.x, tn = blockIdx.y, tid = threadIdx.x;
#pragma unroll
  for (int i = 0; i < 16; ++i) {
    int idx = i * 256 + tid;
    int kr = idx >> 6, nc = idx & 63;
    int kk = tk * 64 + kr;
    const float* s = (kk < split) ? S0 + (size_t)kk * 2048 + tn * 64 + nc
                                  : S1 + (size_t)(kk - split) * 2048 + tn * 64 + nc;
    tile[kr][nc] = *s;
  }
  __syncthreads();
#pragma unroll
  for (int i = 0; i < 16; ++i) {
    int idx = i * 256 + tid;
    int nr = idx >> 6, kc = idx & 63;
    Out[(size_t)(tn * 64 + nr) * Ktot + tk * 64 + kc] = f2bf(tile[kc][nr]);
  }
}

// ---------------- 3) x_proj GEMM: 128x128 tile, BK=32, global_load_lds ------
__global__ __launch_bounds__(256) void k_gemm(const unsigned short* __restrict__ A,
                                              const unsigned short* __restrict__ Bt,
                                              const float* __restrict__ bias,
                                              unsigned short* __restrict__ xproj) {
  __shared__ __attribute__((aligned(16))) unsigned short At[128 * 32];
  __shared__ __attribute__((aligned(16))) unsigned short Bs[128 * 32];
  int tn0 = blockIdx.x * 128, tm0 = blockIdx.y * 128;
  int tid = threadIdx.x, wave = tid >> 6, lane = tid & 63;
  int wr = wave >> 1, wc = wave & 1;
  f32x4 acc[4][4] = {};

  for (int kt = 0; kt < 32; ++kt) {
    __syncthreads();
#pragma unroll
    for (int i = 0; i < 2; ++i) {
      int cb = i * 256 + wave * 64;
      int c = cb + lane;
      const unsigned short* ga = A + (size_t)(tm0 + (c >> 2)) * 1024 + kt * 32 + (c & 3) * 8;
      __builtin_amdgcn_global_load_lds((const __attribute__((address_space(1))) void*)ga,
                                       (__attribute__((address_space(3))) void*)(At + cb * 8),
                                       16, 0, 0);
      const unsigned short* gb = Bt + (size_t)(tn0 + (c >> 2)) * 1024 + kt * 32 + (c & 3) * 8;
      __builtin_amdgcn_global_load_lds((const __attribute__((address_space(1))) void*)gb,
                                       (__attribute__((address_space(3))) void*)(Bs + cb * 8),
                                       16, 0, 0);
    }
    __syncthreads();
    short8 af[4], bf[4];
#pragma unroll
    for (int m = 0; m < 4; ++m)
      af[m] = *(const short8*)(At + (wr * 64 + m * 16 + (lane & 15)) * 32 + (lane >> 4) * 8);
#pragma unroll
    for (int n = 0; n < 4; ++n)
      bf[n] = *(const short8*)(Bs + (wc * 64 + n * 16 + (lane & 15)) * 32 + (lane >> 4) * 8);
#pragma unroll
    for (int m = 0; m < 4; ++m)
#pragma unroll
      for (int n = 0; n < 4; ++n)
        acc[m][n] = __builtin_amdgcn_mfma_f32_16x16x32_bf16(af[m], bf[n], acc[m][n], 0, 0, 0);
  }

#pragma unroll
  for (int n = 0; n < 4; ++n) {
    int cg = tn0 + wc * 64 + n * 16 + (lane & 15);
    float bv = bias[cg];
#pragma unroll
    for (int m = 0; m < 4; ++m) {
#pragma unroll
      for (int rr = 0; rr < 4; ++rr) {
        int rg = tm0 + wr * 64 + m * 16 + ((lane >> 4) << 2) + rr;  // r = b*512+s
        int orow = ((rg & 511) << 6) | (rg >> 9);                   // s*64+b
        xproj[(size_t)orow * 2048 + cg] = f2bf(acc[m][n][rr] + bv);
      }
    }
  }
}

// ---------------- 4) persistent recurrence, epoch-stamped ----------------
// wg = (bg = blockIdx>>4, dg = blockIdx&15). Group = 16 wgs sharing bg.
// wave w = gate w; owns V^T rows [w*512+dg*32, +32) (vfrag[2][16]).
// sh = stamped h, dwords: sh[slot][batch][d] = (bf16 h) | (epoch<<16).
// Wave w polls/stages the d-chunk [w*128, w*128+128) for 16 batches.
__global__ __launch_bounds__(256, 1) void k_lstm(const unsigned short* __restrict__ xproj,
                                                 const unsigned short* __restrict__ Vt,
                                                 unsigned* __restrict__ sh,
                                                 float* __restrict__ out) {
  __shared__ unsigned short h_lds[16][520];   // +8 pad: 2-way banks on b128 ops
  __shared__ float gbuf[4][16][32];
  __shared__ __attribute__((aligned(16))) unsigned short xbuf[4][16][32];

  int g = blockIdx.x;
  int bg = g >> 4, dg = g & 15;
  int tid = threadIdx.x, wave = tid >> 6, lane = tid & 63;

  // V fragments resident across the whole kernel: 2 tiles x 16 k-steps
  short8 vfrag[2][16];
#pragma unroll
  for (int hh = 0; hh < 2; ++hh)
#pragma unroll
    for (int kt = 0; kt < 16; ++kt) {
      int n = wave * 512 + dg * 32 + hh * 16 + (lane & 15);
      vfrag[hh][kt] = *(const short8*)(Vt + (size_t)n * 512 + kt * 32 + (lane >> 4) * 8);
    }

  float c0 = 0.f, c1 = 0.f;          // cell state in registers
  int br = tid >> 4;                 // batch row 0..15
  int dc = (tid & 15) * 2;           // d col (pair)
  int batch = bg * 16 + br;
  int dglob = dg * 32 + dc;

  int xb = tid >> 4, xq = (tid >> 2) & 3, xs = tid & 3;
  const unsigned short* xrow =
      xproj + (size_t)(bg * 16 + xb) * 2048 + xq * 512 + dg * 32 + xs * 8;

  int arow = lane & 15, acol8 = (lane >> 4) * 8;   // fragment row / col-base
  // poll base: this wave's chunk, this lane's slice (dword pointer)
  const unsigned* hl0 = sh + (size_t)(bg * 16 + arow) * 512 + wave * 128 + acol8;
  unsigned* hstore0 = sh + (size_t)batch * 512 + dglob;   // producer slot base

  short8 xv = *(const short8*)xrow;  // x_proj for t=0

  for (int t = 0; t < 512; ++t) {
    // ---- poll own chunk of stamped h(t) until every stamp == t ----
    unsigned tsh = (unsigned)t << 16;
    const unsigned* pb = hl0 + ((t & 1) ? 32768 : 0);   // slot = 64*512 dwords
    u32x4v q0, q1, q2, q3, q4, q5, q6, q7;
    while (true) {
      asm volatile(
          "global_load_dwordx4 %0, %8, off sc0 sc1\n\t"
          "global_load_dwordx4 %1, %8, off offset:16 sc0 sc1\n\t"
          "global_load_dwordx4 %2, %8, off offset:128 sc0 sc1\n\t"
          "global_load_dwordx4 %3, %8, off offset:144 sc0 sc1\n\t"
          "global_load_dwordx4 %4, %8, off offset:256 sc0 sc1\n\t"
          "global_load_dwordx4 %5, %8, off offset:272 sc0 sc1\n\t"
          "global_load_dwordx4 %6, %8, off offset:384 sc0 sc1\n\t"
          "global_load_dwordx4 %7, %8, off offset:400 sc0 sc1\n\t"
          "s_waitcnt vmcnt(0)"
          : "=&v"(q0), "=&v"(q1), "=&v"(q2), "=&v"(q3),
            "=&v"(q4), "=&v"(q5), "=&v"(q6), "=&v"(q7)
          : "v"(pb)
          : "memory");
      unsigned acc =
          (q0[0] ^ tsh) | (q0[1] ^ tsh) | (q0[2] ^ tsh) | (q0[3] ^ tsh) |
          (q1[0] ^ tsh) | (q1[1] ^ tsh) | (q1[2] ^ tsh) | (q1[3] ^ tsh) |
          (q2[0] ^ tsh) | (q2[1] ^ tsh) | (q2[2] ^ tsh) | (q2[3] ^ tsh) |
          (q3[0] ^ tsh) | (q3[1] ^ tsh) | (q3[2] ^ tsh) | (q3[3] ^ tsh) |
          (q4[0] ^ tsh) | (q4[1] ^ tsh) | (q4[2] ^ tsh) | (q4[3] ^ tsh) |
          (q5[0] ^ tsh) | (q5[1] ^ tsh) | (q5[2] ^ tsh) | (q5[3] ^ tsh) |
          (q6[0] ^ tsh) | (q6[1] ^ tsh) | (q6[2] ^ tsh) | (q6[3] ^ tsh) |
          (q7[0] ^ tsh) | (q7[1] ^ tsh) | (q7[2] ^ tsh) | (q7[3] ^ tsh);
      if (__all((acc >> 16) == 0)) break;   // hi16 of every dword == t
    }

    // ---- strip stamps, stage this wave's chunk into LDS ----
    {
      u32x4v p;
      p[0] = (q0[0] & 0xffffu) | (q0[1] << 16);
      p[1] = (q0[2] & 0xffffu) | (q0[3] << 16);
      p[2] = (q1[0] & 0xffffu) | (q1[1] << 16);
      p[3] = (q1[2] & 0xffffu) | (q1[3] << 16);
      *(u32x4v*)&h_lds[arow][(wave * 4 + 0) * 32 + acol8] = p;
      p[0] = (q2[0] & 0xffffu) | (q2[1] << 16);
      p[1] = (q2[2] & 0xffffu) | (q2[3] << 16);
      p[2] = (q3[0] & 0xffffu) | (q3[1] << 16);
      p[3] = (q3[2] & 0xffffu) | (q3[3] << 16);
      *(u32x4v*)&h_lds[arow][(wave * 4 + 1) * 32 + acol8] = p;
      p[0] = (q4[0] & 0xffffu) | (q4[1] << 16);
      p[1] = (q4[2] & 0xffffu) | (q4[3] << 16);
      p[2] = (q5[0] & 0xffffu) | (q5[1] << 16);
      p[3] = (q5[2] & 0xffffu) | (q5[3] << 16);
      *(u32x4v*)&h_lds[arow][(wave * 4 + 2) * 32 + acol8] = p;
      p[0] = (q6[0] & 0xffffu) | (q6[1] << 16);
      p[1] = (q6[2] & 0xffffu) | (q6[3] << 16);
      p[2] = (q7[0] & 0xffffu) | (q7[1] << 16);
      p[3] = (q7[2] & 0xffffu) | (q7[3] << 16);
      *(u32x4v*)&h_lds[arow][(wave * 4 + 3) * 32 + acol8] = p;
    }

    // prefetch next step's x_proj (normal cached load; drains well before
    // the next poll's vmcnt(0))
    short8 xvn = xv;
    if (t < 511) xvn = *(const short8*)(xrow + (size_t)(t + 1) * 131072);

    __syncthreads();   // h_lds fully staged (barrier A)

    // ---- recurrent GEMM: A = h fragments from LDS, B = resident V ----
    f32x4 a0 = {0.f, 0.f, 0.f, 0.f}, a1 = {0.f, 0.f, 0.f, 0.f};
#pragma unroll
    for (int kt = 0; kt < 16; ++kt) {
      short8 af = *(const short8*)&h_lds[arow][kt * 32 + acol8];
      a0 = __builtin_amdgcn_mfma_f32_16x16x32_bf16(af, vfrag[0][kt], a0, 0, 0, 0);
      a1 = __builtin_amdgcn_mfma_f32_16x16x32_bf16(af, vfrag[1][kt], a1, 0, 0, 0);
    }

    *(short8*)&xbuf[xq][xb][xs * 8] = xv;
#pragma unroll
    for (int rr = 0; rr < 4; ++rr) {
      gbuf[wave][((lane >> 4) << 2) + rr][lane & 15] = a0[rr];
      gbuf[wave][((lane >> 4) << 2) + rr][16 + (lane & 15)] = a1[rr];
    }
    __syncthreads();   // gates ready (barrier B)

    // ---- elementwise: 2 (b,d) elems per thread ----
    f32x2 vi = *(const f32x2*)&gbuf[0][br][dc];
    f32x2 vf = *(const f32x2*)&gbuf[1][br][dc];
    f32x2 vg = *(const f32x2*)&gbuf[2][br][dc];
    f32x2 vo = *(const f32x2*)&gbuf[3][br][dc];
    unsigned xi = *(const unsigned*)&xbuf[0][br][dc];
    unsigned xf = *(const unsigned*)&xbuf[1][br][dc];
    unsigned xg = *(const unsigned*)&xbuf[2][br][dc];
    unsigned xo = *(const unsigned*)&xbuf[3][br][dc];

    float i0 = sigm(vi[0] + bf2f((unsigned short)xi));
    float i1 = sigm(vi[1] + bf2f((unsigned short)(xi >> 16)));
    float f0v = sigm(vf[0] + bf2f((unsigned short)xf));
    float f1v = sigm(vf[1] + bf2f((unsigned short)(xf >> 16)));
    float g0 = tanh_f(vg[0] + bf2f((unsigned short)xg));
    float g1 = tanh_f(vg[1] + bf2f((unsigned short)(xg >> 16)));
    float o0 = sigm(vo[0] + bf2f((unsigned short)xo));
    float o1 = sigm(vo[1] + bf2f((unsigned short)(xo >> 16)));

    c0 = f0v * c0 + i0 * g0;
    c1 = f1v * c1 + i1 * g1;
    float h0 = o0 * tanh_f(c0);
    float h1 = o1 * tanh_f(c1);

    // ---- stamped h publish: fire-and-forget, device scope ----
    unsigned st = (unsigned)(t + 1) << 16;
    u32x2v sd;
    sd[0] = (unsigned)f2bf(h0) | st;
    sd[1] = (unsigned)f2bf(h1) | st;
    unsigned* hp = hstore0 + (((t + 1) & 1) ? 32768 : 0);
    asm volatile("global_store_dwordx2 %0, %1, off sc0 sc1"
                 :: "v"(hp), "v"(sd) : "memory");

    f32x2 hv = {h0, h1};
    *(f32x2*)(out + (size_t)batch * 262144 + (size_t)t * 512 + dglob) = hv;
    if (t == 511) {
      *(f32x2*)(out + 16777216 + batch * 512 + dglob) = hv;
      f32x2 cv = {c0, c1};
      *(f32x2*)(out + 16809984 + batch * 512 + dglob) = cv;
    }
    xv = xvn;
    // no end-of-step barrier: the stamped-store -> poll dependency is the
    // inter-step sync; LDS cross-step hazards are covered by it (a wave can
    // only reach step t+1's LDS writes after its wg's step-t elementwise
    // stores were observed, which postdate all step-t LDS reads).
  }
}

extern "C" void kernel_launch(void* const* d_in, const int* in_sizes, int n_in,
                              void* d_out, int out_size, void* d_ws, size_t ws_size,
                              hipStream_t stream) {
  const float* cas  = (const float*)d_in[0];
  const float* soc  = (const float*)d_in[1];
  const float* W    = (const float*)d_in[2];
  const float* U    = (const float*)d_in[3];
  const float* V    = (const float*)d_in[4];
  const float* bias = (const float*)d_in[5];
  float* out = (float*)d_out;
  char* ws = (char*)d_ws;

  unsigned short* xproj = (unsigned short*)(ws + 262144);  // 134,217,728 B
  unsigned short* Xcat  = xproj + (size_t)32768 * 2048;    // 67,108,864 B
  unsigned short* WUt   = Xcat + (size_t)32768 * 1024;     // 4,194,304 B
  unsigned short* Vt    = WUt + (size_t)2048 * 1024;       // 2,097,152 B
  // stamped h buffer reuses the head of Xcat (dead after k_gemm): 256KB
  unsigned* sh = (unsigned*)Xcat;

  k_convX<<<16384, 256, 0, stream>>>(cas, soc, Xcat);
  k_transpose<<<dim3(16, 32), 256, 0, stream>>>(W, U, 512, 1024, WUt);
  k_transpose<<<dim3(8, 32), 256, 0, stream>>>(V, V, 512, 512, Vt);
  k_gemm<<<dim3(16, 256), 256, 0, stream>>>(Xcat, WUt, bias, xproj);
  // zero stamps (epoch 0, h = 0) for both ping-pong slots — after gemm,
  // before the recurrence (Xcat is dead by now)
  hipMemsetAsync(sh, 0, 262144, stream);
  k_lstm<<<64, 256, 0, stream>>>(xproj, Vt, sh, out);
}

// Round 5
// 1374.144 us; speedup vs baseline: 4.5912x; 1.3294x over previous
//
#include <hip/hip_runtime.h>
#include <stdint.h>

// SharedLSTM: B=64, S=512, D=512.
//  out = concat(hidden_seq [64,512,512], h_T [64,512], c_T [64,512]) fp32.
//
// Round 5 = round 4 (epoch-stamped h, fire-and-forget sc0sc1 stores, poll the
// data itself) + two critical-path fixes found in post-mortem:
//  (a) x_proj prefetch hoisted ABOVE the poll loop: its ~900cy HBM latency
//      was being drained by barrier A's implicit vmcnt(0) AFTER the poll,
//      serializing into every step. Now it overlaps the poll RT.
//  (b) poll loads linear-coalesced: wave w polls rows [4w,4w+4) x 512 cols
//      (contiguous 8KB), 1KB contiguous per instruction instead of 16
//      scattered 64B transactions. LDS staging remap to match.
//
// ws layout:
//   [262144, +134217728)  x_proj bf16 [32768][2048]
//   then Xcat (67MB) — head reused after k_gemm as stamped-h sh (256KB,
//        memset between k_gemm and k_lstm), WUt (4MB), Vt (2MB)

typedef __attribute__((ext_vector_type(8))) short short8;
typedef __attribute__((ext_vector_type(4))) float f32x4;
typedef __attribute__((ext_vector_type(2))) float f32x2;
typedef __attribute__((ext_vector_type(4))) unsigned int u32x4v;
typedef __attribute__((ext_vector_type(2))) unsigned int u32x2v;

__device__ __forceinline__ unsigned short f2bf(float x) {
  union { float f; unsigned v; } c; c.f = x;
  unsigned r = (c.v + 0x7fffu + ((c.v >> 16) & 1u)) >> 16;  // RNE
  return (unsigned short)r;
}
__device__ __forceinline__ float bf2f(unsigned short u) {
  union { unsigned v; float f; } c; c.v = (unsigned)u << 16; return c.f;
}
__device__ __forceinline__ float sigm(float x) { return 1.f / (1.f + __expf(-x)); }
__device__ __forceinline__ float tanh_f(float x) { return 1.f - 2.f / (__expf(2.f * x) + 1.f); }

// ---------------- 1) concat + fp32->bf16 ----------------
__global__ __launch_bounds__(256) void k_convX(const float* __restrict__ cas,
                                               const float* __restrict__ soc,
                                               unsigned short* __restrict__ Xcat) {
  size_t i = ((size_t)blockIdx.x * 256 + threadIdx.x) * 8;  // elem in 32768*1024
  int r = (int)(i >> 10), k0 = (int)(i & 1023);
  const float* src = (k0 < 512) ? cas + (size_t)r * 512 + k0
                                : soc + (size_t)r * 512 + (k0 - 512);
  f32x4 a = *(const f32x4*)src;
  f32x4 b = *(const f32x4*)(src + 4);
  short8 o;
  o[0] = (short)f2bf(a[0]); o[1] = (short)f2bf(a[1]);
  o[2] = (short)f2bf(a[2]); o[3] = (short)f2bf(a[3]);
  o[4] = (short)f2bf(b[0]); o[5] = (short)f2bf(b[1]);
  o[6] = (short)f2bf(b[2]); o[7] = (short)f2bf(b[3]);
  *(short8*)(Xcat + i) = o;
}

// ---------------- 2) transpose + convert: Out[n][kk] = src(kk,n) -----------
__global__ __launch_bounds__(256) void k_transpose(const float* __restrict__ S0,
                                                   const float* __restrict__ S1,
                                                   int split, int Ktot,
                                                   unsigned short* __restrict__ Out) {
  __shared__ float tile[64][65];
  int tk = blockIdx.x, tn = blockIdx.y, tid = threadIdx.x;
#pragma unroll
  for (int i = 0; i < 16; ++i) {
    int idx = i * 256 + tid;
    int kr = idx >> 6, nc = idx & 63;
    int kk = tk * 64 + kr;
    const float* s = (kk < split) ? S0 + (size_t)kk * 2048 + tn * 64 + nc
                                  : S1 + (size_t)(kk - split) * 2048 + tn * 64 + nc;
    tile[kr][nc] = *s;
  }
  __syncthreads();
#pragma unroll
  for (int i = 0; i < 16; ++i) {
    int idx = i * 256 + tid;
    int nr = idx >> 6, kc = idx & 63;
    Out[(size_t)(tn * 64 + nr) * Ktot + tk * 64 + kc] = f2bf(tile[kc][nr]);
  }
}

// ---------------- 3) x_proj GEMM: 128x128 tile, BK=32, global_load_lds ------
__global__ __launch_bounds__(256) void k_gemm(const unsigned short* __restrict__ A,
                                              const unsigned short* __restrict__ Bt,
                                              const float* __restrict__ bias,
                                              unsigned short* __restrict__ xproj) {
  __shared__ __attribute__((aligned(16))) unsigned short At[128 * 32];
  __shared__ __attribute__((aligned(16))) unsigned short Bs[128 * 32];
  int tn0 = blockIdx.x * 128, tm0 = blockIdx.y * 128;
  int tid = threadIdx.x, wave = tid >> 6, lane = tid & 63;
  int wr = wave >> 1, wc = wave & 1;
  f32x4 acc[4][4] = {};

  for (int kt = 0; kt < 32; ++kt) {
    __syncthreads();
#pragma unroll
    for (int i = 0; i < 2; ++i) {
      int cb = i * 256 + wave * 64;
      int c = cb + lane;
      const unsigned short* ga = A + (size_t)(tm0 + (c >> 2)) * 1024 + kt * 32 + (c & 3) * 8;
      __builtin_amdgcn_global_load_lds((const __attribute__((address_space(1))) void*)ga,
                                       (__attribute__((address_space(3))) void*)(At + cb * 8),
                                       16, 0, 0);
      const unsigned short* gb = Bt + (size_t)(tn0 + (c >> 2)) * 1024 + kt * 32 + (c & 3) * 8;
      __builtin_amdgcn_global_load_lds((const __attribute__((address_space(1))) void*)gb,
                                       (__attribute__((address_space(3))) void*)(Bs + cb * 8),
                                       16, 0, 0);
    }
    __syncthreads();
    short8 af[4], bf[4];
#pragma unroll
    for (int m = 0; m < 4; ++m)
      af[m] = *(const short8*)(At + (wr * 64 + m * 16 + (lane & 15)) * 32 + (lane >> 4) * 8);
#pragma unroll
    for (int n = 0; n < 4; ++n)
      bf[n] = *(const short8*)(Bs + (wc * 64 + n * 16 + (lane & 15)) * 32 + (lane >> 4) * 8);
#pragma unroll
    for (int m = 0; m < 4; ++m)
#pragma unroll
      for (int n = 0; n < 4; ++n)
        acc[m][n] = __builtin_amdgcn_mfma_f32_16x16x32_bf16(af[m], bf[n], acc[m][n], 0, 0, 0);
  }

#pragma unroll
  for (int n = 0; n < 4; ++n) {
    int cg = tn0 + wc * 64 + n * 16 + (lane & 15);
    float bv = bias[cg];
#pragma unroll
    for (int m = 0; m < 4; ++m) {
#pragma unroll
      for (int rr = 0; rr < 4; ++rr) {
        int rg = tm0 + wr * 64 + m * 16 + ((lane >> 4) << 2) + rr;  // r = b*512+s
        int orow = ((rg & 511) << 6) | (rg >> 9);                   // s*64+b
        xproj[(size_t)orow * 2048 + cg] = f2bf(acc[m][n][rr] + bv);
      }
    }
  }
}

// ---------------- 4) persistent recurrence, epoch-stamped ----------------
// wg = (bg = blockIdx>>4, dg = blockIdx&15). Group = 16 wgs sharing bg.
// wave w = gate w; owns V^T rows [w*512+dg*32, +32) (vfrag[2][16]).
// sh dwords: sh[slot][batch][d] = (bf16 h) | (epoch<<16).
// Wave w polls the LINEAR slab rows [bg*16+4w, +4) x 512 d (8KB), fully
// coalesced (1KB contiguous per instruction), stages into LDS.
__global__ __launch_bounds__(256, 1) void k_lstm(const unsigned short* __restrict__ xproj,
                                                 const unsigned short* __restrict__ Vt,
                                                 unsigned* __restrict__ sh,
                                                 float* __restrict__ out) {
  __shared__ unsigned short h_lds[16][520];   // 1040B rows: 16B-aligned
  __shared__ float gbuf[4][16][32];
  __shared__ __attribute__((aligned(16))) unsigned short xbuf[4][16][32];

  int g = blockIdx.x;
  int bg = g >> 4, dg = g & 15;
  int tid = threadIdx.x, wave = tid >> 6, lane = tid & 63;

  // V fragments resident across the whole kernel: 2 tiles x 16 k-steps
  short8 vfrag[2][16];
#pragma unroll
  for (int hh = 0; hh < 2; ++hh)
#pragma unroll
    for (int kt = 0; kt < 16; ++kt) {
      int n = wave * 512 + dg * 32 + hh * 16 + (lane & 15);
      vfrag[hh][kt] = *(const short8*)(Vt + (size_t)n * 512 + kt * 32 + (lane >> 4) * 8);
    }

  float c0 = 0.f, c1 = 0.f;          // cell state in registers
  int br = tid >> 4;                 // batch row 0..15
  int dc = (tid & 15) * 2;           // d col (pair)
  int batch = bg * 16 + br;
  int dglob = dg * 32 + dc;

  int xb = tid >> 4, xq = (tid >> 2) & 3, xs = tid & 3;
  const unsigned short* xrow =
      xproj + (size_t)(bg * 16 + xb) * 2048 + xq * 512 + dg * 32 + xs * 8;

  int arow = lane & 15, acol8 = (lane >> 4) * 8;   // MFMA fragment row/col-base

  // linear poll base: wave w, lane l -> dword (bg*16)*512 + w*2048 + l*4
  const unsigned* pl0 = sh + (size_t)bg * 8192 + wave * 2048 + lane * 4;
  unsigned* hstore0 = sh + (size_t)batch * 512 + dglob;   // producer base

  short8 xv = *(const short8*)xrow;  // x_proj for t=0

  for (int t = 0; t < 512; ++t) {
    // ---- prefetch next step's x_proj FIRST: overlaps the poll RT, and is
    //      long done by barrier A (was previously serialized after the poll)
    short8 xvn = xv;
    if (t < 511) xvn = *(const short8*)(xrow + (size_t)(t + 1) * 131072);

    // ---- poll own linear slab of stamped h(t) until every stamp == t ----
    unsigned tsh = (unsigned)t << 16;
    const unsigned* pb = pl0 + ((t & 1) ? 32768 : 0);   // slot = 64*512 dwords
    const unsigned* pb4 = pb + 1024;                    // offset range > 4095B
    u32x4v q0, q1, q2, q3, q4, q5, q6, q7;
    while (true) {
      asm volatile(
          "global_load_dwordx4 %0, %8, off sc0 sc1\n\t"
          "global_load_dwordx4 %1, %8, off offset:1024 sc0 sc1\n\t"
          "global_load_dwordx4 %2, %8, off offset:2048 sc0 sc1\n\t"
          "global_load_dwordx4 %3, %8, off offset:3072 sc0 sc1\n\t"
          "global_load_dwordx4 %4, %9, off sc0 sc1\n\t"
          "global_load_dwordx4 %5, %9, off offset:1024 sc0 sc1\n\t"
          "global_load_dwordx4 %6, %9, off offset:2048 sc0 sc1\n\t"
          "global_load_dwordx4 %7, %9, off offset:3072 sc0 sc1\n\t"
          "s_waitcnt vmcnt(0)"
          : "=&v"(q0), "=&v"(q1), "=&v"(q2), "=&v"(q3),
            "=&v"(q4), "=&v"(q5), "=&v"(q6), "=&v"(q7)
          : "v"(pb), "v"(pb4)
          : "memory");
      unsigned acc =
          (q0[0] ^ tsh) | (q0[1] ^ tsh) | (q0[2] ^ tsh) | (q0[3] ^ tsh) |
          (q1[0] ^ tsh) | (q1[1] ^ tsh) | (q1[2] ^ tsh) | (q1[3] ^ tsh) |
          (q2[0] ^ tsh) | (q2[1] ^ tsh) | (q2[2] ^ tsh) | (q2[3] ^ tsh) |
          (q3[0] ^ tsh) | (q3[1] ^ tsh) | (q3[2] ^ tsh) | (q3[3] ^ tsh) |
          (q4[0] ^ tsh) | (q4[1] ^ tsh) | (q4[2] ^ tsh) | (q4[3] ^ tsh) |
          (q5[0] ^ tsh) | (q5[1] ^ tsh) | (q5[2] ^ tsh) | (q5[3] ^ tsh) |
          (q6[0] ^ tsh) | (q6[1] ^ tsh) | (q6[2] ^ tsh) | (q6[3] ^ tsh) |
          (q7[0] ^ tsh) | (q7[1] ^ tsh) | (q7[2] ^ tsh) | (q7[3] ^ tsh);
      if (__all((acc >> 16) == 0)) break;   // hi16 of every dword == t
    }

    // ---- strip stamps, stage into LDS ----
    // load j covers dwords w*2048 + j*256 + lane*4 .. +4
    //  -> row = w*4 + (j>>1), col = (j&1)*256 + lane*4
    {
      int r0 = wave * 4;
      int cA = lane * 4, cB = 256 + lane * 4;
      u32x2v p;
      p[0] = (q0[0] & 0xffffu) | (q0[1] << 16);
      p[1] = (q0[2] & 0xffffu) | (q0[3] << 16);
      *(u32x2v*)&h_lds[r0 + 0][cA] = p;
      p[0] = (q1[0] & 0xffffu) | (q1[1] << 16);
      p[1] = (q1[2] & 0xffffu) | (q1[3] << 16);
      *(u32x2v*)&h_lds[r0 + 0][cB] = p;
      p[0] = (q2[0] & 0xffffu) | (q2[1] << 16);
      p[1] = (q2[2] & 0xffffu) | (q2[3] << 16);
      *(u32x2v*)&h_lds[r0 + 1][cA] = p;
      p[0] = (q3[0] & 0xffffu) | (q3[1] << 16);
      p[1] = (q3[2] & 0xffffu) | (q3[3] << 16);
      *(u32x2v*)&h_lds[r0 + 1][cB] = p;
      p[0] = (q4[0] & 0xffffu) | (q4[1] << 16);
      p[1] = (q4[2] & 0xffffu) | (q4[3] << 16);
      *(u32x2v*)&h_lds[r0 + 2][cA] = p;
      p[0] = (q5[0] & 0xffffu) | (q5[1] << 16);
      p[1] = (q5[2] & 0xffffu) | (q5[3] << 16);
      *(u32x2v*)&h_lds[r0 + 2][cB] = p;
      p[0] = (q6[0] & 0xffffu) | (q6[1] << 16);
      p[1] = (q6[2] & 0xffffu) | (q6[3] << 16);
      *(u32x2v*)&h_lds[r0 + 3][cA] = p;
      p[0] = (q7[0] & 0xffffu) | (q7[1] << 16);
      p[1] = (q7[2] & 0xffffu) | (q7[3] << 16);
      *(u32x2v*)&h_lds[r0 + 3][cB] = p;
    }

    __syncthreads();   // h_lds fully staged (barrier A)

    // ---- recurrent GEMM: A = h fragments from LDS, B = resident V ----
    f32x4 a0 = {0.f, 0.f, 0.f, 0.f}, a1 = {0.f, 0.f, 0.f, 0.f};
#pragma unroll
    for (int kt = 0; kt < 16; ++kt) {
      short8 af = *(const short8*)&h_lds[arow][kt * 32 + acol8];
      a0 = __builtin_amdgcn_mfma_f32_16x16x32_bf16(af, vfrag[0][kt], a0, 0, 0, 0);
      a1 = __builtin_amdgcn_mfma_f32_16x16x32_bf16(af, vfrag[1][kt], a1, 0, 0, 0);
    }

    *(short8*)&xbuf[xq][xb][xs * 8] = xv;
#pragma unroll
    for (int rr = 0; rr < 4; ++rr) {
      gbuf[wave][((lane >> 4) << 2) + rr][lane & 15] = a0[rr];
      gbuf[wave][((lane >> 4) << 2) + rr][16 + (lane & 15)] = a1[rr];
    }
    __syncthreads();   // gates ready (barrier B)

    // ---- elementwise: 2 (b,d) elems per thread ----
    f32x2 vi = *(const f32x2*)&gbuf[0][br][dc];
    f32x2 vf = *(const f32x2*)&gbuf[1][br][dc];
    f32x2 vg = *(const f32x2*)&gbuf[2][br][dc];
    f32x2 vo = *(const f32x2*)&gbuf[3][br][dc];
    unsigned xi = *(const unsigned*)&xbuf[0][br][dc];
    unsigned xf = *(const unsigned*)&xbuf[1][br][dc];
    unsigned xg = *(const unsigned*)&xbuf[2][br][dc];
    unsigned xo = *(const unsigned*)&xbuf[3][br][dc];

    float i0 = sigm(vi[0] + bf2f((unsigned short)xi));
    float i1 = sigm(vi[1] + bf2f((unsigned short)(xi >> 16)));
    float f0v = sigm(vf[0] + bf2f((unsigned short)xf));
    float f1v = sigm(vf[1] + bf2f((unsigned short)(xf >> 16)));
    float g0 = tanh_f(vg[0] + bf2f((unsigned short)xg));
    float g1 = tanh_f(vg[1] + bf2f((unsigned short)(xg >> 16)));
    float o0 = sigm(vo[0] + bf2f((unsigned short)xo));
    float o1 = sigm(vo[1] + bf2f((unsigned short)(xo >> 16)));

    c0 = f0v * c0 + i0 * g0;
    c1 = f1v * c1 + i1 * g1;
    float h0 = o0 * tanh_f(c0);
    float h1 = o1 * tanh_f(c1);

    // ---- stamped h publish: fire-and-forget, device scope ----
    unsigned st = (unsigned)(t + 1) << 16;
    u32x2v sd;
    sd[0] = (unsigned)f2bf(h0) | st;
    sd[1] = (unsigned)f2bf(h1) | st;
    unsigned* hp = hstore0 + (((t + 1) & 1) ? 32768 : 0);
    asm volatile("global_store_dwordx2 %0, %1, off sc0 sc1"
                 :: "v"(hp), "v"(sd) : "memory");

    f32x2 hv = {h0, h1};
    *(f32x2*)(out + (size_t)batch * 262144 + (size_t)t * 512 + dglob) = hv;
    if (t == 511) {
      *(f32x2*)(out + 16777216 + batch * 512 + dglob) = hv;
      f32x2 cv = {c0, c1};
      *(f32x2*)(out + 16809984 + batch * 512 + dglob) = cv;
    }
    xv = xvn;
    // no end-of-step barrier: stamped-store -> poll is the inter-step sync.
  }
}

extern "C" void kernel_launch(void* const* d_in, const int* in_sizes, int n_in,
                              void* d_out, int out_size, void* d_ws, size_t ws_size,
                              hipStream_t stream) {
  const float* cas  = (const float*)d_in[0];
  const float* soc  = (const float*)d_in[1];
  const float* W    = (const float*)d_in[2];
  const float* U    = (const float*)d_in[3];
  const float* V    = (const float*)d_in[4];
  const float* bias = (const float*)d_in[5];
  float* out = (float*)d_out;
  char* ws = (char*)d_ws;

  unsigned short* xproj = (unsigned short*)(ws + 262144);  // 134,217,728 B
  unsigned short* Xcat  = xproj + (size_t)32768 * 2048;    // 67,108,864 B
  unsigned short* WUt   = Xcat + (size_t)32768 * 1024;     // 4,194,304 B
  unsigned short* Vt    = WUt + (size_t)2048 * 1024;       // 2,097,152 B
  // stamped h buffer reuses the head of Xcat (dead after k_gemm): 256KB
  unsigned* sh = (unsigned*)Xcat;

  k_convX<<<16384, 256, 0, stream>>>(cas, soc, Xcat);
  k_transpose<<<dim3(16, 32), 256, 0, stream>>>(W, U, 512, 1024, WUt);
  k_transpose<<<dim3(8, 32), 256, 0, stream>>>(V, V, 512, 512, Vt);
  k_gemm<<<dim3(16, 256), 256, 0, stream>>>(Xcat, WUt, bias, xproj);
  // zero stamps (epoch 0, h = 0) for both ping-pong slots
  hipMemsetAsync(sh, 0, 262144, stream);
  k_lstm<<<64, 256, 0, stream>>>(xproj, Vt, sh, out);
}